// Round 6
// baseline (5784.121 us; speedup 1.0000x reference)
//
#include <hip/hip_runtime.h>
#include <math.h>

// Residual VQ: x (262144,128) fp32, codebooks (3,256,128) fp32.
// Output: [indices as float (262144*3)] ++ [quantized (262144*128)].
//
// ARITHMETIC CONTRACT (round 3, absmax=0 — do not change):
//   M_k  = OpenBLAS sgemm K-loop: sequential FMA chain j=0..127, acc init 0
//   A    = np.sum(r*r): pairwise_sum 8-accumulator scheme, products rounded
//          separately (fmaf(x,x,0) = single-rounded product, blocks fusion)
//   d2_k = (A - 2.0f*M_k) + B_k ; argmin strict < ascending k
//   residual -= q ; quantized = (q0 + q1) + q2  (elementwise fp32, ref order)
//
// ROUND 10: SPLIT-DIM LANE-PAIR STRUCTURE.
// Learned so far: (a) RA spills a 128-float live set no matter the source
// idiom (r3-r7); (b) LDS-resident residual caps occupancy at ~1 wave/SIMD
// (r8/r9); (c) item-per-lane needs ONE fresh wave-uniform codebook scalar
// per FMA instr -> s_load path = 2-3-deep SGPR window stall (r8 diagnosis),
// LDS-broadcast path = CU-shared LDS pipe oversubscribed 3-4x at >=4
// waves/CU; (d) r9's 147KB LDS never launched (proven envelope is 128KB).
// This design: lane 2i+h holds dims h*64..h*64+63 of item i in 64 NAMED
// registers (RA-tolerable). Codebook loads gain an h-dependent offset ->
// genuinely divergent -> global_load_dwordx4 (vector pipe, deep vmcnt,
// L2-resident codebook); 2 transactions/instr serve the whole wave.
// Bit-exactness of the j=0..127 sequential chain via handoff: h=0 folds
// j<64 from 0, shfl_xor(1) passes the partial, h=1 continues the SAME
// left-fold on j>=64 (exact). 1-deep software pipeline keeps both halves
// busy: step g = {h=0: partials of group g | h=1: finals of group g-1};
// one shfl per chain serves both directions. A (pairwise-8) splits the
// same way (acc handoff after 8 terms each). Argmin wholly on h=0
// (ascending k, strict <). 65 steps/codebook (prolog+drain ~1.5%).
// LDS: 3KB (s_B only). No main-loop barriers. ~120 VGPR -> 3-4 waves/SIMD.

constexpr int kItems = 262144;
constexpr int kDim   = 128;
constexpr int kNcb   = 3;
constexpr int kK     = 256;
constexpr int kBlock = 256;          // 4 waves; 128 items/block (2 lanes/item)

__device__ __forceinline__ float sq_rn(float x) {
    return __builtin_fmaf(x, x, 0.0f);   // single-rounded product, blocks contraction
}
#define F3(a, b, acc) __builtin_fmaf((a), (b), (acc))

// ONLY for codebook B_k staging (global reads)
__device__ __forceinline__ float np_sumsq128(const float* __restrict__ p) {
    float a0 = sq_rn(p[0]), a1 = sq_rn(p[1]), a2 = sq_rn(p[2]), a3 = sq_rn(p[3]),
          a4 = sq_rn(p[4]), a5 = sq_rn(p[5]), a6 = sq_rn(p[6]), a7 = sq_rn(p[7]);
    #pragma unroll
    for (int i = 8; i < 128; i += 8) {
        a0 = a0 + sq_rn(p[i + 0]); a1 = a1 + sq_rn(p[i + 1]);
        a2 = a2 + sq_rn(p[i + 2]); a3 = a3 + sq_rn(p[i + 3]);
        a4 = a4 + sq_rn(p[i + 4]); a5 = a5 + sq_rn(p[i + 5]);
        a6 = a6 + sq_rn(p[i + 6]); a7 = a7 + sq_rn(p[i + 7]);
    }
    return ((a0 + a1) + (a2 + a3)) + ((a4 + a5) + (a6 + a7));
}

// ---- 16 float4-groups of the 64 named residual scalars (this lane's half)
#define ROWS16(M) \
  M(0,r0,r1,r2,r3)     M(1,r4,r5,r6,r7)     M(2,r8,r9,r10,r11)    M(3,r12,r13,r14,r15) \
  M(4,r16,r17,r18,r19) M(5,r20,r21,r22,r23) M(6,r24,r25,r26,r27)  M(7,r28,r29,r30,r31) \
  M(8,r32,r33,r34,r35) M(9,r36,r37,r38,r39) M(10,r40,r41,r42,r43) M(11,r44,r45,r46,r47) \
  M(12,r48,r49,r50,r51) M(13,r52,r53,r54,r55) M(14,r56,r57,r58,r59) M(15,r60,r61,r62,r63)

#define DECL4(i,a,b,c,d)  float a, b, c, d;
#define LD4(i,a,b,c,d)    { const float4 v_ = xv4[i]; a = v_.x; b = v_.y; c = v_.z; d = v_.w; }
#define SUB4(i,a,b,c,d)   { const float4 v_ = cw4[i]; a = a - v_.x; b = b - v_.y; c = c - v_.z; d = d - v_.w; }

// A pairwise-8: local dim j' = 4i+e; global j = h*64 + j'; acc = j&7 = (4i+e)&7
// (h*64 is 0 mod 8). uu/ww are 8-elem, ALL indices compile-time constants.
#define SQ4U(i,a,b,c,d) \
  uu[(4*(i)+0)&7] += sq_rn(a); uu[(4*(i)+1)&7] += sq_rn(b); \
  uu[(4*(i)+2)&7] += sq_rn(c); uu[(4*(i)+3)&7] += sq_rn(d);
#define SQ4W(i,a,b,c,d) \
  ww[(4*(i)+0)&7] += sq_rn(a); ww[(4*(i)+1)&7] += sq_rn(b); \
  ww[(4*(i)+2)&7] += sq_rn(c); ww[(4*(i)+3)&7] += sq_rn(d);

// pass1: own-half fold from 0 (truth on h=0). swap. pass2: continuation fold
// on the received accs (truth on h=1; exact left-fold continuation). combine
// on h=1, swap back -> A valid on h=0 (h=1's A is unused garbage).
#define COMPUTE_A() { \
  float uu[8] = {0.f,0.f,0.f,0.f,0.f,0.f,0.f,0.f}; \
  ROWS16(SQ4U) \
  float ww[8]; \
  ww[0]=__shfl_xor(uu[0],1); ww[1]=__shfl_xor(uu[1],1); \
  ww[2]=__shfl_xor(uu[2],1); ww[3]=__shfl_xor(uu[3],1); \
  ww[4]=__shfl_xor(uu[4],1); ww[5]=__shfl_xor(uu[5],1); \
  ww[6]=__shfl_xor(uu[6],1); ww[7]=__shfl_xor(uu[7],1); \
  ROWS16(SQ4W) \
  const float A2_ = ((ww[0]+ww[1])+(ww[2]+ww[3]))+((ww[4]+ww[5])+(ww[6]+ww[7])); \
  A = __shfl_xor(A2_, 1); }

// 4-chain fold of one float4-group: chain mc accumulates its row's dims in
// ascending j' (x,y,z,w), groups s ascending -> per-chain order = ascending j.
#define FOLD16(s,a,b,c,d) { \
  const float4 e0_ = p0[s], e1_ = p1[s], e2_ = p2[s], e3_ = p3[s]; \
  m0=F3(a,e0_.x,m0); m1=F3(a,e1_.x,m1); m2=F3(a,e2_.x,m2); m3=F3(a,e3_.x,m3); \
  m0=F3(b,e0_.y,m0); m1=F3(b,e1_.y,m1); m2=F3(b,e2_.y,m2); m3=F3(b,e3_.y,m3); \
  m0=F3(c,e0_.z,m0); m1=F3(c,e1_.z,m1); m2=F3(c,e2_.z,m2); m3=F3(c,e3_.z,m3); \
  m0=F3(d,e0_.w,m0); m1=F3(d,e1_.w,m1); m2=F3(d,e2_.w,m2); m3=F3(d,e3_.w,m3); }

// Scan one codebook. Step g: h=0 folds partials of group g (start 0);
// h=1 folds finals of group g-1 (start = received partial). One shfl per
// chain swaps roles' data. Argmin on h=0, guarded g>=1, ascending k,
// strict <. g=0: h=1 folds clamped rows (garbage, never argmin'd).
// g=64: h=0 folds clamped rows (garbage, never received). Then broadcast
// bi to h=1; residual update + A recompute for next codebook.
#define SCAN_CB(cc, selvar) { \
  const float* cbc = cb + (size_t)(cc) * kK * kDim + h * 64; \
  float best = INFINITY; int bi = 0; \
  float rc0 = 0.f, rc1 = 0.f, rc2 = 0.f, rc3 = 0.f; \
  _Pragma("unroll 1") \
  for (int g = 0; g <= 64; ++g) { \
    int gg = h ? g - 1 : g; gg = gg < 0 ? 0 : (gg > 63 ? 63 : gg); \
    const float4* p0 = (const float4*)(cbc + (size_t)(gg*4+0) * kDim); \
    const float4* p1 = (const float4*)(cbc + (size_t)(gg*4+1) * kDim); \
    const float4* p2 = (const float4*)(cbc + (size_t)(gg*4+2) * kDim); \
    const float4* p3 = (const float4*)(cbc + (size_t)(gg*4+3) * kDim); \
    float m0 = h ? rc0 : 0.f, m1 = h ? rc1 : 0.f, \
          m2 = h ? rc2 : 0.f, m3 = h ? rc3 : 0.f; \
    ROWS16(FOLD16) \
    const float f0 = __shfl_xor(m0,1), f1 = __shfl_xor(m1,1), \
                f2 = __shfl_xor(m2,1), f3 = __shfl_xor(m3,1); \
    if (g) { \
      const int kb = (g - 1) * 4; \
      const float b0 = s_B[(cc)*kK+kb+0], b1 = s_B[(cc)*kK+kb+1], \
                  b2 = s_B[(cc)*kK+kb+2], b3 = s_B[(cc)*kK+kb+3]; \
      const float t0 = (A - 2.0f*f0) + b0, t1 = (A - 2.0f*f1) + b1, \
                  t2 = (A - 2.0f*f2) + b2, t3 = (A - 2.0f*f3) + b3; \
      if (t0 < best) { best = t0; bi = kb + 0; } \
      if (t1 < best) { best = t1; bi = kb + 1; } \
      if (t2 < best) { best = t2; bi = kb + 2; } \
      if (t3 < best) { best = t3; bi = kb + 3; } \
    } \
    rc0 = f0; rc1 = f1; rc2 = f2; rc3 = f3; \
  } \
  const int rb_ = __shfl_xor(bi, 1); \
  selvar = h ? rb_ : bi; \
  if ((cc) < kNcb - 1) { \
    const float4* cw4 = (const float4*)(cb + ((size_t)(cc)*kK + selvar)*kDim + h*64); \
    ROWS16(SUB4) \
    COMPUTE_A() \
  } }

__global__ __launch_bounds__(kBlock, 3) void rvq_kernel(
    const float* __restrict__ x,
    const float* __restrict__ cb,
    float* __restrict__ out)
{
    __shared__ float s_B[kNcb * kK];   // 3 KiB
    const int tid = threadIdx.x;
    for (int m = tid; m < kNcb * kK; m += kBlock)
        s_B[m] = np_sumsq128(cb + (size_t)m * kDim);
    __syncthreads();

    const int h = tid & 1;                              // dim-half of the pair
    const int item = blockIdx.x * (kBlock / 2) + (tid >> 1);
    const float4* xv4 = (const float4*)(x + (size_t)item * kDim + h * 64);

    ROWS16(DECL4)          // 64 named scalars: this lane's residual half
    ROWS16(LD4)            // residual = x (own half)

    float A;
    COMPUTE_A()            // A = sum(x*x), split pairwise-8 handoff

    int sel0, sel1, sel2;
    SCAN_CB(0, sel0)
    SCAN_CB(1, sel1)
    SCAN_CB(2, sel2)

    // ---- outputs
    float* out_idx = out;                             // (items, 3) as float
    float* out_q   = out + (size_t)kItems * kNcb;     // (items, 128)
    if (!h) {
        out_idx[(size_t)item * kNcb + 0] = (float)sel0;
        out_idx[(size_t)item * kNcb + 1] = (float)sel1;
        out_idx[(size_t)item * kNcb + 2] = (float)sel2;
    }
    const float4* q0 = (const float4*)(cb + ((size_t)0 * kK + sel0) * kDim + h * 64);
    const float4* q1 = (const float4*)(cb + ((size_t)1 * kK + sel1) * kDim + h * 64);
    const float4* q2 = (const float4*)(cb + ((size_t)2 * kK + sel2) * kDim + h * 64);
    float* qo = out_q + (size_t)item * kDim + h * 64;
    #pragma unroll
    for (int i = 0; i < 16; ++i) {
        const float4 v0 = q0[i], v1 = q1[i], v2 = q2[i];
        float4 w;
        w.x = (v0.x + v1.x) + v2.x;
        w.y = (v0.y + v1.y) + v2.y;
        w.z = (v0.z + v1.z) + v2.z;
        w.w = (v0.w + v1.w) + v2.w;   // ((0+q0)+q1)+q2 in fp32, ref order
        ((float4*)qo)[i] = w;
    }
}

extern "C" void kernel_launch(void* const* d_in, const int* in_sizes, int n_in,
                              void* d_out, int out_size, void* d_ws, size_t ws_size,
                              hipStream_t stream) {
    const float* x  = (const float*)d_in[0];
    const float* cb = (const float*)d_in[1];
    float* out = (float*)d_out;
    // 2 lanes per item -> kItems*2 threads total
    rvq_kernel<<<(kItems * 2) / kBlock, kBlock, 0, stream>>>(x, cb, out);
}

// Round 7
// 1059.229 us; speedup vs baseline: 5.4607x; 5.4607x over previous
//
#include <hip/hip_runtime.h>
#include <math.h>

// Residual VQ: x (262144,128) fp32, codebooks (3,256,128) fp32.
// Output: [indices as float (262144*3)] ++ [quantized (262144*128)].
//
// ARITHMETIC CONTRACT (round 3, absmax=0 — do not change):
//   M_k  = OpenBLAS sgemm K-loop: sequential FMA chain j=0..127, acc init 0
//   A    = np.sum(r*r): pairwise_sum 8-accumulator scheme, products rounded
//          separately (fmaf(x,x,0) = single-rounded product, blocks fusion)
//   d2_k = (A - 2.0f*M_k) + B_k ; argmin strict < ascending k
//   residual -= q ; quantized = (q0 + q1) + q2  (elementwise fp32, ref order)
//
// ROUND 11: 2 items/lane x quarter-dims, codebook LDS-broadcast at 8:1.
// Unified diagnosis r3-r10: the codebook must be re-broadcast per item at
// 1 float per FMA-instr; any delivery instr (s_load / ds_read_b128 / v-load)
// carries <=16 useful bytes = 4 FMA-instr. 4:1 is delivery-bound (1.5x over
// VALU on the LDS pipe; latency-dead on scalar/VMEM paths). This design:
// lane (pair p, quarter q) holds dims [32q,32q+32) of items {2p, 2p+1} in
// 64 registers (under the proven RA wall). One ds_read_b128 codebook quad
// feeds 2 items x 4 FMAs = 8:1 -> LDS demand ~0.22 instr/cyc/CU. Bit-exact
// j=0..127 chain via 4-piece left fold (r10's proven handoff, generalized):
// quarter q continues the partial from q-1; software pipeline (quarter q
// works on k-group g-q) keeps all lanes busy; 8 shfl_up per step. A: same
// 4-round serial handoff (exact). Argmin at q=3 lanes (ascending k, strict
// <). Codebook staged per 128-row phase (64 KiB dynamic LDS, quarter-
// interleaved so the 4 quarters' quads land in disjoint banks).

constexpr int kItems = 262144;
constexpr int kDim   = 128;
constexpr int kNcb   = 3;
constexpr int kK     = 256;
constexpr int kBlock = 512;          // 8 waves; 256 items/block

__device__ __forceinline__ float sq_rn(float x) {
    return __builtin_fmaf(x, x, 0.0f);   // single-rounded product, blocks contraction
}
#define F3(a, b, c) __builtin_fmaf((a), (b), (c))

// ONLY for codebook B_k staging (global reads)
__device__ __forceinline__ float np_sumsq128(const float* __restrict__ p) {
    float a0 = sq_rn(p[0]), a1 = sq_rn(p[1]), a2 = sq_rn(p[2]), a3 = sq_rn(p[3]),
          a4 = sq_rn(p[4]), a5 = sq_rn(p[5]), a6 = sq_rn(p[6]), a7 = sq_rn(p[7]);
    #pragma unroll
    for (int i = 8; i < 128; i += 8) {
        a0 = a0 + sq_rn(p[i + 0]); a1 = a1 + sq_rn(p[i + 1]);
        a2 = a2 + sq_rn(p[i + 2]); a3 = a3 + sq_rn(p[i + 3]);
        a4 = a4 + sq_rn(p[i + 4]); a5 = a5 + sq_rn(p[i + 5]);
        a6 = a6 + sq_rn(p[i + 6]); a7 = a7 + sq_rn(p[i + 7]);
    }
    return ((a0 + a1) + (a2 + a3)) + ((a4 + a5) + (a6 + a7));
}

// ---- residual: 2 items x 8 float4 (dims 32q..32q+31), all named ----------
#define DECLR(u)  float4 RA_##u, RB_##u;
#define LOADR(u)  RA_##u = xa4[u]; RB_##u = xb4[u];
#define R8(M) M(0) M(1) M(2) M(3) M(4) M(5) M(6) M(7)

// A-fold of this lane's 32 terms ON TOP of accs a0..a7 (in-place, ascending
// local j' = 4u+e; acc = (32q + 4u + e) & 7 = (4u+e)&7 since 32q%8==0)
#define AFOLD(R, a0,a1,a2,a3,a4,a5,a6,a7) \
  a0 = a0 + sq_rn(R##_0.x); a1 = a1 + sq_rn(R##_0.y); a2 = a2 + sq_rn(R##_0.z); a3 = a3 + sq_rn(R##_0.w); \
  a4 = a4 + sq_rn(R##_1.x); a5 = a5 + sq_rn(R##_1.y); a6 = a6 + sq_rn(R##_1.z); a7 = a7 + sq_rn(R##_1.w); \
  a0 = a0 + sq_rn(R##_2.x); a1 = a1 + sq_rn(R##_2.y); a2 = a2 + sq_rn(R##_2.z); a3 = a3 + sq_rn(R##_2.w); \
  a4 = a4 + sq_rn(R##_3.x); a5 = a5 + sq_rn(R##_3.y); a6 = a6 + sq_rn(R##_3.z); a7 = a7 + sq_rn(R##_3.w); \
  a0 = a0 + sq_rn(R##_4.x); a1 = a1 + sq_rn(R##_4.y); a2 = a2 + sq_rn(R##_4.z); a3 = a3 + sq_rn(R##_4.w); \
  a4 = a4 + sq_rn(R##_5.x); a5 = a5 + sq_rn(R##_5.y); a6 = a6 + sq_rn(R##_5.z); a7 = a7 + sq_rn(R##_5.w); \
  a0 = a0 + sq_rn(R##_6.x); a1 = a1 + sq_rn(R##_6.y); a2 = a2 + sq_rn(R##_6.z); a3 = a3 + sq_rn(R##_6.w); \
  a4 = a4 + sq_rn(R##_7.x); a5 = a5 + sq_rn(R##_7.y); a6 = a6 + sq_rn(R##_7.z); a7 = a7 + sq_rn(R##_7.w);

// A = np.sum(r*r): 4-round SERIAL handoff across the quarter chain.
// Round r: lanes q==r receive the 8 partial accs from q==r-1 and fold their
// own 32 terms on top (exact left fold). Valid at q==3.
#define ACOMPUTE(R, Avar) { \
  float u0=0.f,u1=0.f,u2=0.f,u3=0.f,u4=0.f,u5=0.f,u6=0.f,u7=0.f; \
  if (q == 0) { AFOLD(R,u0,u1,u2,u3,u4,u5,u6,u7) } \
  { float w0=__shfl_up(u0,1),w1=__shfl_up(u1,1),w2=__shfl_up(u2,1),w3=__shfl_up(u3,1), \
          w4=__shfl_up(u4,1),w5=__shfl_up(u5,1),w6=__shfl_up(u6,1),w7=__shfl_up(u7,1); \
    if (q == 1) { u0=w0;u1=w1;u2=w2;u3=w3;u4=w4;u5=w5;u6=w6;u7=w7; \
                  AFOLD(R,u0,u1,u2,u3,u4,u5,u6,u7) } } \
  { float w0=__shfl_up(u0,1),w1=__shfl_up(u1,1),w2=__shfl_up(u2,1),w3=__shfl_up(u3,1), \
          w4=__shfl_up(u4,1),w5=__shfl_up(u5,1),w6=__shfl_up(u6,1),w7=__shfl_up(u7,1); \
    if (q == 2) { u0=w0;u1=w1;u2=w2;u3=w3;u4=w4;u5=w5;u6=w6;u7=w7; \
                  AFOLD(R,u0,u1,u2,u3,u4,u5,u6,u7) } } \
  { float w0=__shfl_up(u0,1),w1=__shfl_up(u1,1),w2=__shfl_up(u2,1),w3=__shfl_up(u3,1), \
          w4=__shfl_up(u4,1),w5=__shfl_up(u5,1),w6=__shfl_up(u6,1),w7=__shfl_up(u7,1); \
    if (q == 3) { u0=w0;u1=w1;u2=w2;u3=w3;u4=w4;u5=w5;u6=w6;u7=w7; \
                  AFOLD(R,u0,u1,u2,u3,u4,u5,u6,u7) } } \
  Avar = ((u0+u1)+(u2+u3))+((u4+u5)+(u6+u7)); }

// one quad column u: 4 ds_read_b128 (shared by both items) + 32 FMAs.
// chain m*r folds e=0..3 ascending within u, u ascending across calls
// -> per-chain order = ascending local j' -> ascending global j (with the
// pipeline handoff supplying the prefix from lower quarters). rbase =
// (gg*4)*32 + q ; row r at rbase + r*32.
#define FOLD_U(u) { \
  const float4 c0 = s_cb[rbase +      (u)*4]; \
  const float4 c1 = s_cb[rbase + 32 + (u)*4]; \
  const float4 c2 = s_cb[rbase + 64 + (u)*4]; \
  const float4 c3 = s_cb[rbase + 96 + (u)*4]; \
  ma0=F3(RA_##u.x,c0.x,ma0); ma0=F3(RA_##u.y,c0.y,ma0); ma0=F3(RA_##u.z,c0.z,ma0); ma0=F3(RA_##u.w,c0.w,ma0); \
  ma1=F3(RA_##u.x,c1.x,ma1); ma1=F3(RA_##u.y,c1.y,ma1); ma1=F3(RA_##u.z,c1.z,ma1); ma1=F3(RA_##u.w,c1.w,ma1); \
  ma2=F3(RA_##u.x,c2.x,ma2); ma2=F3(RA_##u.y,c2.y,ma2); ma2=F3(RA_##u.z,c2.z,ma2); ma2=F3(RA_##u.w,c2.w,ma2); \
  ma3=F3(RA_##u.x,c3.x,ma3); ma3=F3(RA_##u.y,c3.y,ma3); ma3=F3(RA_##u.z,c3.z,ma3); ma3=F3(RA_##u.w,c3.w,ma3); \
  mb0=F3(RB_##u.x,c0.x,mb0); mb0=F3(RB_##u.y,c0.y,mb0); mb0=F3(RB_##u.z,c0.z,mb0); mb0=F3(RB_##u.w,c0.w,mb0); \
  mb1=F3(RB_##u.x,c1.x,mb1); mb1=F3(RB_##u.y,c1.y,mb1); mb1=F3(RB_##u.z,c1.z,mb1); mb1=F3(RB_##u.w,c1.w,mb1); \
  mb2=F3(RB_##u.x,c2.x,mb2); mb2=F3(RB_##u.y,c2.y,mb2); mb2=F3(RB_##u.z,c2.z,mb2); mb2=F3(RB_##u.w,c2.w,mb2); \
  mb3=F3(RB_##u.x,c3.x,mb3); mb3=F3(RB_##u.y,c3.y,mb3); mb3=F3(RB_##u.z,c3.z,mb3); mb3=F3(RB_##u.w,c3.w,mb3); }

// residual -= q (elementwise, ref order): this lane's quarter of both items
#define UPDR(R, selv) { \
  const float4* cw = (const float4*)(cb + ((size_t)c * kK + (selv)) * (size_t)kDim) + q * 8; \
  R##_0.x -= cw[0].x; R##_0.y -= cw[0].y; R##_0.z -= cw[0].z; R##_0.w -= cw[0].w; \
  R##_1.x -= cw[1].x; R##_1.y -= cw[1].y; R##_1.z -= cw[1].z; R##_1.w -= cw[1].w; \
  R##_2.x -= cw[2].x; R##_2.y -= cw[2].y; R##_2.z -= cw[2].z; R##_2.w -= cw[2].w; \
  R##_3.x -= cw[3].x; R##_3.y -= cw[3].y; R##_3.z -= cw[3].z; R##_3.w -= cw[3].w; \
  R##_4.x -= cw[4].x; R##_4.y -= cw[4].y; R##_4.z -= cw[4].z; R##_4.w -= cw[4].w; \
  R##_5.x -= cw[5].x; R##_5.y -= cw[5].y; R##_5.z -= cw[5].z; R##_5.w -= cw[5].w; \
  R##_6.x -= cw[6].x; R##_6.y -= cw[6].y; R##_6.z -= cw[6].z; R##_6.w -= cw[6].w; \
  R##_7.x -= cw[7].x; R##_7.y -= cw[7].y; R##_7.z -= cw[7].z; R##_7.w -= cw[7].w; }

__global__ __launch_bounds__(kBlock, 4) void rvq_kernel(
    const float* __restrict__ x,
    const float* __restrict__ cb,
    float* __restrict__ out)
{
    extern __shared__ float4 s_cb[];        // 4096 float4 = 64 KiB (one phase,
                                            // layout [row128][jq8][q4])
    __shared__ float s_B[kNcb * kK];        // 3 KiB

    const int tid  = threadIdx.x;
    const int lane = tid & 63;
    const int p    = lane >> 2;             // pair index 0..15
    const int q    = lane & 3;              // quarter 0..3
    const int wave = tid >> 6;              // 0..7

    // B_k = np.sum(cb*cb, axis=-1), bit-exact
    for (int m = tid; m < kNcb * kK; m += kBlock)
        s_B[m] = np_sumsq128(cb + (size_t)m * kDim);

    // items: 2 per lane-pair group
    const size_t ia = (size_t)blockIdx.x * 256 + wave * 32 + p * 2 + 0;
    const size_t ib = ia + 1;
    const float4* xa4 = (const float4*)(x + ia * kDim + q * 32);
    const float4* xb4 = (const float4*)(x + ib * kDim + q * 32);

    R8(DECLR)
    R8(LOADR)

    float Aa, Ab;
    ACOMPUTE(RA, Aa)
    ACOMPUTE(RB, Ab)

    int sA0=0,sA1=0,sA2=0,sB0=0,sB1=0,sB2=0;

    #pragma unroll
    for (int c = 0; c < kNcb; ++c) {
        float bestA = INFINITY, bestB = INFINITY;
        int   biA = 0, biB = 0;
        const int cB = c * kK;

        #pragma unroll
        for (int ph = 0; ph < 2; ++ph) {
            __syncthreads();   // previous phase fully consumed
            // stage 128 rows, quarter-interleaved: LDS[row*32 + jq*4 + qq]
            {
                const float4* gsrc = (const float4*)cb + ((size_t)(c * kK + ph * 128)) * 32;
                #pragma unroll
                for (int u = 0; u < 8; ++u) {
                    const int gi  = u * kBlock + tid;        // coalesced
                    const float4 v = gsrc[gi];
                    const int row = gi >> 5, rem = gi & 31;
                    s_cb[row * 32 + (rem & 7) * 4 + (rem >> 3)] = v;
                }
            }
            __syncthreads();

            const int kbase = ph * 128;
            float va0=0.f,va1=0.f,va2=0.f,va3=0.f,vb0=0.f,vb1=0.f,vb2=0.f,vb3=0.f;

            #pragma unroll 1
            for (int g = 0; g < 35; ++g) {
                int gg = g - q; gg = gg < 0 ? 0 : (gg > 31 ? 31 : gg);
                const int rbase = gg * 128 + q;              // (gg*4)*32 + q
                float ma0 = q ? va0 : 0.f, ma1 = q ? va1 : 0.f,
                      ma2 = q ? va2 : 0.f, ma3 = q ? va3 : 0.f;
                float mb0 = q ? vb0 : 0.f, mb1 = q ? vb1 : 0.f,
                      mb2 = q ? vb2 : 0.f, mb3 = q ? vb3 : 0.f;
                R8(FOLD_U)
                if (q == 3 && g >= 3) {                      // group g-3 final
                    const int kb = kbase + (g - 3) * 4;
                    float d;
                    d = (Aa - 2.0f*ma0) + s_B[cB+kb+0]; if (d < bestA) { bestA=d; biA=kb+0; }
                    d = (Aa - 2.0f*ma1) + s_B[cB+kb+1]; if (d < bestA) { bestA=d; biA=kb+1; }
                    d = (Aa - 2.0f*ma2) + s_B[cB+kb+2]; if (d < bestA) { bestA=d; biA=kb+2; }
                    d = (Aa - 2.0f*ma3) + s_B[cB+kb+3]; if (d < bestA) { bestA=d; biA=kb+3; }
                    d = (Ab - 2.0f*mb0) + s_B[cB+kb+0]; if (d < bestB) { bestB=d; biB=kb+0; }
                    d = (Ab - 2.0f*mb1) + s_B[cB+kb+1]; if (d < bestB) { bestB=d; biB=kb+1; }
                    d = (Ab - 2.0f*mb2) + s_B[cB+kb+2]; if (d < bestB) { bestB=d; biB=kb+2; }
                    d = (Ab - 2.0f*mb3) + s_B[cB+kb+3]; if (d < bestB) { bestB=d; biB=kb+3; }
                }
                va0 = __shfl_up(ma0,1); va1 = __shfl_up(ma1,1);
                va2 = __shfl_up(ma2,1); va3 = __shfl_up(ma3,1);
                vb0 = __shfl_up(mb0,1); vb1 = __shfl_up(mb1,1);
                vb2 = __shfl_up(mb2,1); vb3 = __shfl_up(mb3,1);
            }
        }

        const int selA = __shfl(biA, lane | 3);   // broadcast from q==3
        const int selB = __shfl(biB, lane | 3);
        if (c == 0) { sA0 = selA; sB0 = selB; }
        else if (c == 1) { sA1 = selA; sB1 = selB; }
        else { sA2 = selA; sB2 = selB; }

        if (c < kNcb - 1) {
            UPDR(RA, selA)
            UPDR(RB, selB)
            ACOMPUTE(RA, Aa)
            ACOMPUTE(RB, Ab)
        }
    }

    // ---- outputs
    float* out_idx = out;                             // (items, 3) as float
    float* out_q   = out + (size_t)kItems * kNcb;     // (items, 128)
    if (q == 0) {
        out_idx[ia*3+0] = (float)sA0; out_idx[ia*3+1] = (float)sA1; out_idx[ia*3+2] = (float)sA2;
        out_idx[ib*3+0] = (float)sB0; out_idx[ib*3+1] = (float)sB1; out_idx[ib*3+2] = (float)sB2;
    }
    {
        const float4* g0 = (const float4*)(cb + ((size_t)0*kK + sA0)*kDim) + q*8;
        const float4* g1 = (const float4*)(cb + ((size_t)1*kK + sA1)*kDim) + q*8;
        const float4* g2 = (const float4*)(cb + ((size_t)2*kK + sA2)*kDim) + q*8;
        float4* qo = (float4*)(out_q + ia * kDim) + q*8;
        #pragma unroll
        for (int u = 0; u < 8; ++u) {
            const float4 v0 = g0[u], v1 = g1[u], v2 = g2[u];
            float4 w;
            w.x = (v0.x + v1.x) + v2.x; w.y = (v0.y + v1.y) + v2.y;
            w.z = (v0.z + v1.z) + v2.z; w.w = (v0.w + v1.w) + v2.w;
            qo[u] = w;                 // ((0+q0)+q1)+q2 in fp32, ref order
        }
    }
    {
        const float4* g0 = (const float4*)(cb + ((size_t)0*kK + sB0)*kDim) + q*8;
        const float4* g1 = (const float4*)(cb + ((size_t)1*kK + sB1)*kDim) + q*8;
        const float4* g2 = (const float4*)(cb + ((size_t)2*kK + sB2)*kDim) + q*8;
        float4* qo = (float4*)(out_q + ib * kDim) + q*8;
        #pragma unroll
        for (int u = 0; u < 8; ++u) {
            const float4 v0 = g0[u], v1 = g1[u], v2 = g2[u];
            float4 w;
            w.x = (v0.x + v1.x) + v2.x; w.y = (v0.y + v1.y) + v2.y;
            w.z = (v0.z + v1.z) + v2.z; w.w = (v0.w + v1.w) + v2.w;
            qo[u] = w;
        }
    }
}

extern "C" void kernel_launch(void* const* d_in, const int* in_sizes, int n_in,
                              void* d_out, int out_size, void* d_ws, size_t ws_size,
                              hipStream_t stream) {
    const float* x  = (const float*)d_in[0];
    const float* cb = (const float*)d_in[1];
    float* out = (float*)d_out;
    static bool attr_set = false;
    if (!attr_set) {
        hipFuncSetAttribute((const void*)rvq_kernel,
                            hipFuncAttributeMaxDynamicSharedMemorySize, 65536);
        attr_set = true;
    }
    // 256 items per block (2 lanes... 4 lanes per 2 items): kItems/256 blocks
    rvq_kernel<<<kItems / 256, kBlock, 65536, stream>>>(x, cb, out);
}